// Round 16
// baseline (109.677 us; speedup 1.0000x reference)
//
#include <hip/hip_runtime.h>

typedef __attribute__((ext_vector_type(4))) float f32x4;
typedef __attribute__((ext_vector_type(8))) __bf16 bf16x8;
typedef __attribute__((ext_vector_type(4))) __bf16 bf16x4;
typedef __attribute__((ext_vector_type(2))) unsigned int u32x2;

// tr_read with compile-time offset folded into the DS immediate.
template<int OFF>
__device__ __forceinline__ u32x2 tr_read_o(unsigned base){
    u32x2 d;
    asm volatile("ds_read_b64_tr_b16 %0, %1 offset:%c2"
                 : "=v"(d) : "v"(base), "i"(OFF));
    return d;
}
__device__ __forceinline__ bf16x8 frag_cat(u32x2 a, u32x2 b){
    union { u32x2 u[2]; bf16x8 f; } c; c.u[0] = a; c.u[1] = b; return c.f;
}

// ws layout (floats):
//   x1   @ 0       (65536)
//   vs   @ 65536   (65536)    v row-group-swizzled [row/4][64][4]  (row GLOBAL)
//   Q1   @ 131072  (262144)   q@attn_w1 + attn_b1   [1024][256]
//   K1s  @ 393216  (262144)   k@attn_w1 row-group-swizzled [row/4][256][4]
//   W'   @ 655360  (16384)    pos_w2@attn_w1        [64][256]
//   part @ 671744  (393216)   per-block softmax partials [2048][192]:
//                             m[64], s[64], a[64]  (exp2 domain)

// ---------------------------------------------------------------------------
// Fused prologue: 272 blocks x 256. (unchanged)
// ---------------------------------------------------------------------------
__global__ void ptb_pre(const float* __restrict__ x,
                        const float* __restrict__ pos,
                        const float* __restrict__ prev_w,
                        const float* __restrict__ prev_b,
                        const float* __restrict__ q_w,
                        const float* __restrict__ k_w,
                        const float* __restrict__ v_w,
                        const float* __restrict__ pos_w2,
                        const float* __restrict__ attn_w1,
                        const float* __restrict__ attn_b1,
                        float* __restrict__ ws,
                        float* __restrict__ out)
{
    const int bid = blockIdx.x;
    const int tid = threadIdx.x;
    __shared__ float xr[256], x1r[256], qsh[256], ksh[256], vsh[256];

    float wcol[64];                       // attn_w1 column `tid`
    #pragma unroll
    for (int c = 0; c < 64; ++c) wcol[c] = attn_w1[c*256 + tid];

    if (bid >= 256){
        xr[tid] = pos_w2[(bid - 256)*256 + tid];
        __syncthreads();
        float* Wp = ws + 655360;
        #pragma unroll
        for (int r = 0; r < 4; ++r){
            float s = 0.f;
            #pragma unroll 16
            for (int c = 0; c < 64; ++c) s += xr[r*64 + c] * wcol[c];
            Wp[((bid - 256)*4 + r)*256 + tid] = s;
        }
        return;
    }

    const int rr  = tid >> 6, d = tid & 63;
    const int row = bid*4 + rr;
    xr[tid] = x[row*64 + d];
    __syncthreads();
    float a = prev_b[d];
    #pragma unroll 16
    for (int c = 0; c < 64; ++c) a += xr[rr*64 + c] * prev_w[c*64 + d];
    x1r[tid] = a;
    ws[row*64 + d] = a;
    __syncthreads();
    float qv = 0.f, kv = 0.f, vv = 0.f;
    #pragma unroll 16
    for (int c = 0; c < 64; ++c){
        float t = x1r[rr*64 + c];
        qv += t * q_w[c*64 + d];
        kv += t * k_w[c*64 + d];
        vv += t * v_w[c*64 + d];
    }
    qsh[tid] = qv; ksh[tid] = kv; vsh[tid] = vv;
    if (tid < 12) out[65536 + bid*12 + tid] = pos[bid*12 + tid];
    __syncthreads();

    // vs store: coalesced transpose via LDS -> vs[bid*256 + d'*4 + r']
    ws[65536 + bid*256 + tid] = vsh[(tid & 3)*64 + (tid >> 2)];

    float* Q1  = ws + 131072;
    float* K1s = ws + 393216;
    const float bb = attn_b1[tid];
    float sq[4], sk[4];
    #pragma unroll
    for (int r = 0; r < 4; ++r){ sq[r] = bb; sk[r] = 0.f; }
    #pragma unroll 16
    for (int c = 0; c < 64; ++c){
        const float wv = wcol[c];
        #pragma unroll
        for (int r = 0; r < 4; ++r){
            sq[r] += qsh[r*64 + c] * wv;
            sk[r] += ksh[r*64 + c] * wv;
        }
    }
    #pragma unroll
    for (int r = 0; r < 4; ++r) Q1[(bid*4 + r)*256 + tid] = sq[r];
    f32x4 kvec = {sk[0], sk[1], sk[2], sk[3]};
    *(f32x4*)&K1s[bid*1024 + tid*4] = kvec;
}

// ---------------------------------------------------------------------------
// Main: 2048 blocks (ib = blk>>1, jh = blk&1 -> 4 j-tiles each).
// Round-16 three-way combo (all individually proven):
// (1) VGPR ~96: exp2 softmax + stageA computes AND commits in one shot (no
//     register carry — rounds 12/15 showed carry costs +32 VGPR).
// (2) LDS 27.9K -> 32768 granted -> 5 blocks/CU capacity: sH1 single-buffer;
//     stageA(t+1) runs at the hb==1 post-B barrier (all sH1 readers of tile
//     t done; stage C reads only sHT; next readers behind loop-top B1).
//     pos deltas prefetched after B1 (3 VGPR) to hide the L2 latency.
// (3) grid 2048 > 4/CU so the 5th block slot is usable (round-12 j-split,
//     exp2-domain partials + ptb_fin merge; fixed cost ~2us).
// Decisive readout: VGPR <= 102 -> 5 waves/SIMD -> occupancy ~25.
// ---------------------------------------------------------------------------
__global__ __launch_bounds__(256) void ptb_main(
    const float* __restrict__ pos,
    const float* __restrict__ pos_w1, const float* __restrict__ pos_b1,
    const float* __restrict__ pos_w2, const float* __restrict__ pos_b2,
    const float* __restrict__ attn_w2, const float* __restrict__ attn_b2,
    const float* __restrict__ ws, float* __restrict__ wsp)
{
    const int blk = blockIdx.x;
    const int ib  = blk >> 1;
    const int jh  = blk & 1;
    const int b   = ib >> 9;
    const int i   = ib & 511;
    const int tid = threadIdx.x;
    const int w   = tid >> 6;
    const int l   = tid & 63;
    const int lg  = l >> 4;
    const int ln  = l & 15;

    // h1 tile (post-relu), XOR-swizzled 16B chunks: [j][h ^ ((j&7)<<3)]
    __shared__ __bf16 sH1[64][64];               // 8 KB (single buffer)
    // H^T half-tile: 128 subtiles (jj*64+E) x 144B (128B data + 16B pad)
    __shared__ __align__(16) char sHT[18432];    // 18 KB
    __shared__ float sPW1[192], sPB1[64], sPOSI[3];

    const float* vs  = ws + 65536;
    const float* Q1  = ws + 131072;
    const float* K1s = ws + 393216;
    const float* Wp  = ws + 655360;

    if (tid < 64) sPB1[tid] = pos_b1[tid];
    if (tid >= 64 && tid < 256) sPW1[tid - 64] = pos_w1[tid - 64];
    if (tid < 3) sPOSI[tid] = pos[(b*512 + i)*3 + tid];

    const int dch  = w*16 + ln;         // this lane's output channel (GEMM2)
    const int Ew   = w*64;              // this wave's hidden-col base (GEMM1')
    const int swzA = (ln & 7) << 3;     // sH1 h-chunk swizzle (row&7 == ln&7)

    const float LOG2E = 1.44269504088896f;

    // ---- register-resident weight B-fragments ----
    bf16x8 w1f[2][4];                   // W' frags
    #pragma unroll
    for (int kf = 0; kf < 2; ++kf)
        #pragma unroll
        for (int et = 0; et < 4; ++et)
            #pragma unroll
            for (int ii = 0; ii < 8; ++ii)
                w1f[kf][et][ii] = (__bf16)Wp[(kf*32 + lg*8 + ii)*256 + Ew + et*16 + ln];
    bf16x8 w2f[8];                      // attn_w2 frags, PRESCALED by log2e
    #pragma unroll
    for (int kf = 0; kf < 8; ++kf)
        #pragma unroll
        for (int ii = 0; ii < 8; ++ii)
            w2f[kf][ii] = (__bf16)(attn_w2[(kf*32 + lg*8 + ii)*64 + dch] * LOG2E);
    bf16x8 pwfw[2];                     // pos_w2 frags (value term — NOT scaled)
    #pragma unroll
    for (int kf = 0; kf < 2; ++kf)
        #pragma unroll
        for (int ii = 0; ii < 8; ++ii)
            pwfw[kf][ii] = (__bf16)pos_w2[(kf*32 + lg*8 + ii)*64 + dch];

    float Q1b[4];
    #pragma unroll
    for (int et = 0; et < 4; ++et) Q1b[et] = Q1[ib*256 + Ew + et*16 + ln];
    const float pb2v = pos_b2[dch];
    const float b2v  = attn_b2[dch] * LOG2E;    // scaled with w2f

    const unsigned sHTb = (unsigned)(unsigned long long)&sHT[0];
    // per-lane tr_read base, loop-invariant: lg-group stride = 2 subtiles = 288B
    const unsigned trbase = sHTb + (unsigned)(lg*288 + ln*8);

    float mrun = -1e30f, srun = 0.f, arun = 0.f;

    // ---- stage A: h1 MLP, compute AND commit in one shot (no carry) ----
    auto stageA = [&](float r0, float r1, float r2){
        #pragma unroll
        for (int kf = 0; kf < 2; ++kf){
            const int hb = kf*32 + lg*8;
            f32x4 wa0 = *(const f32x4*)&sPW1[      hb],   wa1 = *(const f32x4*)&sPW1[      hb+4];
            f32x4 wb0 = *(const f32x4*)&sPW1[ 64 + hb],   wb1 = *(const f32x4*)&sPW1[ 64 + hb+4];
            f32x4 wc0 = *(const f32x4*)&sPW1[128 + hb],   wc1 = *(const f32x4*)&sPW1[128 + hb+4];
            f32x4 bb0 = *(const f32x4*)&sPB1[      hb],   bb1 = *(const f32x4*)&sPB1[      hb+4];
            bf16x8 h1f;
            #pragma unroll
            for (int ii = 0; ii < 4; ++ii){
                float hv0 = bb0[ii] + r0*wa0[ii] + r1*wb0[ii] + r2*wc0[ii];
                float hv1 = bb1[ii] + r0*wa1[ii] + r1*wb1[ii] + r2*wc1[ii];
                h1f[ii]   = (__bf16)fmaxf(hv0, 0.f);
                h1f[ii+4] = (__bf16)fmaxf(hv1, 0.f);
            }
            *(bf16x8*)&sH1[w*16 + ln][(kf*32 + lg*8) ^ swzA] = h1f;
        }
    };
    auto posdelta = [&](int j0a, float& r0, float& r1, float& r2){
        const float* pj = &pos[(b*512 + j0a + w*16 + ln)*3];
        r0 = sPOSI[0] - pj[0];
        r1 = sPOSI[1] - pj[1];
        r2 = sPOSI[2] - pj[2];
    };

    const int t0 = jh*4;
    __syncthreads();
    {
        float r0, r1, r2;
        posdelta(t0 << 6, r0, r1, r2);
        stageA(r0, r1, r2);
    }

    #pragma unroll 1
    for (int t = t0; t < t0 + 4; ++t){
        const int j0 = t << 6;
        __syncthreads();                                    // B1
        // prefetch next tile's pos deltas (3 VGPR; L2 latency hides under B)
        float pr0 = 0.f, pr1 = 0.f, pr2 = 0.f;
        if (t < t0 + 3) posdelta(j0 + 64, pr0, pr1, pr2);
        #pragma unroll 1
        for (int hb = 0; hb < 2; ++hb){
            f32x4 rcs[2];                                   // rpe, carried B->C
            // ============== stage B half: GEMM1' + rpe ================
            #pragma unroll
            for (int jj = 0; jj < 2; ++jj){
                const int jrow = hb*32 + jj*16;
                const int krow = ((b*512 + j0 + jrow) >> 2) + lg;   // GLOBAL row group
                const bf16x8 af0 = *(const bf16x8*)&sH1[jrow + ln][(     lg*8) ^ swzA];
                const bf16x8 af1 = *(const bf16x8*)&sH1[jrow + ln][(32 + lg*8) ^ swzA];
                f32x4 accs[4];
                #pragma unroll
                for (int et = 0; et < 4; ++et){
                    const f32x4 kw4 = *(const f32x4*)&K1s[krow*1024 + (Ew + et*16 + ln)*4];
                    const f32x4 qv4 = {Q1b[et], Q1b[et], Q1b[et], Q1b[et]};
                    accs[et] = qv4 - kw4;
                }
                __builtin_amdgcn_s_setprio(1);
                #pragma unroll
                for (int et = 0; et < 4; ++et)
                    accs[et] = __builtin_amdgcn_mfma_f32_16x16x32_bf16(af0, w1f[0][et], accs[et], 0, 0, 0);
                #pragma unroll
                for (int et = 0; et < 4; ++et)
                    accs[et] = __builtin_amdgcn_mfma_f32_16x16x32_bf16(af1, w1f[1][et], accs[et], 0, 0, 0);
                f32x4 rcv = {pb2v, pb2v, pb2v, pb2v};
                rcv = __builtin_amdgcn_mfma_f32_16x16x32_bf16(af0, pwfw[0], rcv, 0, 0, 0);
                rcv = __builtin_amdgcn_mfma_f32_16x16x32_bf16(af1, pwfw[1], rcv, 0, 0, 0);
                rcs[jj] = rcv;
                __builtin_amdgcn_s_setprio(0);
                #pragma unroll
                for (int et = 0; et < 4; ++et){
                    bf16x4 hp;
                    #pragma unroll
                    for (int ri = 0; ri < 4; ++ri) hp[ri] = (__bf16)fmaxf(accs[et][ri], 0.f);
                    *(bf16x4*)(sHT + (jj*64 + w*16 + et*4 + (ln>>2))*144
                                   + (ln&3)*32 + lg*8) = hp;
                }
            }
            __syncthreads();                                // H half ready
            // all sH1 readers of tile t done after hb==1's barrier:
            // compute AND commit next tile's h1 here (no register carry).
            if (hb == 1 && t < t0 + 3) stageA(pr0, pr1, pr2);
            // ====== stage C half: cross-jj pipelined GEMM2 + softmax ==
            f32x4 accv[2], vvv[2];
            #pragma unroll
            for (int jj = 0; jj < 2; ++jj){
                const int vrow = ((b*512 + j0 + hb*32 + jj*16) >> 2) + lg;
                vvv[jj] = *(const f32x4*)&vs[vrow*256 + dch*4];
            }
            u32x2 h0[16], h1[16];
            // issue jj0's 16 reads (16 outstanding)
            #define TR2A(KF) \
                h0[(KF)*2]   = tr_read_o<(KF)*1152      >(trbase); \
                h0[(KF)*2+1] = tr_read_o<(KF)*1152 + 144>(trbase);
            TR2A(0) TR2A(1) TR2A(2) TR2A(3) TR2A(4) TR2A(5) TR2A(6) TR2A(7)
            #undef TR2A
            asm volatile("s_waitcnt lgkmcnt(8)" ::: "memory");   // h0[0..7] ready
            __builtin_amdgcn_sched_barrier(0);
            {
                f32x4 a0 = {b2v, b2v, b2v, b2v};
                f32x4 a1 = {0.f, 0.f, 0.f, 0.f};
                __builtin_amdgcn_s_setprio(1);
                a0 = __builtin_amdgcn_mfma_f32_16x16x32_bf16(frag_cat(h0[0], h0[1]), w2f[0], a0, 0, 0, 0);
                a1 = __builtin_amdgcn_mfma_f32_16x16x32_bf16(frag_cat(h0[2], h0[3]), w2f[1], a1, 0, 0, 0);
                a0 = __builtin_amdgcn_mfma_f32_16x16x32_bf16(frag_cat(h0[4], h0[5]), w2f[2], a0, 0, 0, 0);
                a1 = __builtin_amdgcn_mfma_f32_16x16x32_bf16(frag_cat(h0[6], h0[7]), w2f[3], a1, 0, 0, 0);
                __builtin_amdgcn_s_setprio(0);
                // issue jj1's first 8 (8 jj0-remain + 8 jj1 outstanding)
                const unsigned trb1 = trbase + 9216u;
                #define TR2B(KF) \
                    h1[(KF)*2]   = tr_read_o<(KF)*1152      >(trb1); \
                    h1[(KF)*2+1] = tr_read_o<(KF)*1152 + 144>(trb1);
                TR2B(0) TR2B(1) TR2B(2) TR2B(3)
                asm volatile("s_waitcnt lgkmcnt(8)" ::: "memory");  // h0[8..15] ready
                __builtin_amdgcn_sched_barrier(0);
                __builtin_amdgcn_s_setprio(1);
                a0 = __builtin_amdgcn_mfma_f32_16x16x32_bf16(frag_cat(h0[8],  h0[9]),  w2f[4], a0, 0, 0, 0);
                a1 = __builtin_amdgcn_mfma_f32_16x16x32_bf16(frag_cat(h0[10], h0[11]), w2f[5], a1, 0, 0, 0);
                a0 = __builtin_amdgcn_mfma_f32_16x16x32_bf16(frag_cat(h0[12], h0[13]), w2f[6], a0, 0, 0, 0);
                a1 = __builtin_amdgcn_mfma_f32_16x16x32_bf16(frag_cat(h0[14], h0[15]), w2f[7], a1, 0, 0, 0);
                __builtin_amdgcn_s_setprio(0);
                accv[0] = a0 + a1;
                // issue jj1's last 8 (16 outstanding)
                TR2B(4) TR2B(5) TR2B(6) TR2B(7)
                #undef TR2B
            }
            asm volatile("s_waitcnt lgkmcnt(8)" ::: "memory");   // h1[0..7] ready
            __builtin_amdgcn_sched_barrier(0);
            {
                f32x4 a0 = {b2v, b2v, b2v, b2v};
                f32x4 a1 = {0.f, 0.f, 0.f, 0.f};
                __builtin_amdgcn_s_setprio(1);
                a0 = __builtin_amdgcn_mfma_f32_16x16x32_bf16(frag_cat(h1[0], h1[1]), w2f[0], a0, 0, 0, 0);
                a1 = __builtin_amdgcn_mfma_f32_16x16x32_bf16(frag_cat(h1[2], h1[3]), w2f[1], a1, 0, 0, 0);
                a0 = __builtin_amdgcn_mfma_f32_16x16x32_bf16(frag_cat(h1[4], h1[5]), w2f[2], a0, 0, 0, 0);
                a1 = __builtin_amdgcn_mfma_f32_16x16x32_bf16(frag_cat(h1[6], h1[7]), w2f[3], a1, 0, 0, 0);
                __builtin_amdgcn_s_setprio(0);
                asm volatile("s_waitcnt lgkmcnt(0)" ::: "memory");
                __builtin_amdgcn_sched_barrier(0);
                __builtin_amdgcn_s_setprio(1);
                a0 = __builtin_amdgcn_mfma_f32_16x16x32_bf16(frag_cat(h1[8],  h1[9]),  w2f[4], a0, 0, 0, 0);
                a1 = __builtin_amdgcn_mfma_f32_16x16x32_bf16(frag_cat(h1[10], h1[11]), w2f[5], a1, 0, 0, 0);
                a0 = __builtin_amdgcn_mfma_f32_16x16x32_bf16(frag_cat(h1[12], h1[13]), w2f[6], a0, 0, 0, 0);
                a1 = __builtin_amdgcn_mfma_f32_16x16x32_bf16(frag_cat(h1[14], h1[15]), w2f[7], a1, 0, 0, 0);
                __builtin_amdgcn_s_setprio(0);
                accv[1] = a0 + a1;
            }
            // one deferred softmax update per half — exp2 domain
            float tmax = fmaxf(fmaxf(fmaxf(accv[0][0], accv[0][1]),
                                     fmaxf(accv[0][2], accv[0][3])),
                               fmaxf(fmaxf(accv[1][0], accv[1][1]),
                                     fmaxf(accv[1][2], accv[1][3])));
            tmax = fmaxf(tmax, __shfl_xor(tmax, 16));
            tmax = fmaxf(tmax, __shfl_xor(tmax, 32));
            const float mnew  = fmaxf(mrun, tmax);
            const float scale = __builtin_amdgcn_exp2f(mrun - mnew);
            srun *= scale; arun *= scale; mrun = mnew;
            #pragma unroll
            for (int jj = 0; jj < 2; ++jj)
                #pragma unroll
                for (int ri = 0; ri < 4; ++ri){
                    const float p = __builtin_amdgcn_exp2f(accv[jj][ri] - mnew);
                    srun += p;
                    arun += p * (vvv[jj][ri] + rcs[jj][ri]);
                }
            if (hb == 0) __syncthreads();                   // WAR: sHT reuse
        }
        // loop top's B1 covers: sH1 WAR/WAW vs next stage B, sHT WAR vs B(t+1)
    }

    arun += __shfl_xor(arun, 16); arun += __shfl_xor(arun, 32);
    srun += __shfl_xor(srun, 16); srun += __shfl_xor(srun, 32);
    if (lg == 0){
        float* P = wsp + 671744 + blk*192;
        P[dch]       = mrun;
        P[64 + dch]  = srun;
        P[128 + dch] = arun;
    }
}

// ---------------------------------------------------------------------------
// Merge the two j-half partials (exp2 domain) + final_linear + residual.
// ---------------------------------------------------------------------------
__global__ void ptb_fin(const float* __restrict__ fin_w,
                        const float* __restrict__ fin_b,
                        const float* __restrict__ ws,
                        float* __restrict__ out)
{
    const int ib  = blockIdx.x;
    const int tid = threadIdx.x;
    const float* P0 = ws + 671744 + (ib*2    )*192;
    const float* P1 = ws + 671744 + (ib*2 + 1)*192;
    __shared__ float sAGG[64];
    const float m0 = P0[tid], s0 = P0[64+tid], a0 = P0[128+tid];
    const float m1 = P1[tid], s1 = P1[64+tid], a1 = P1[128+tid];
    const float M  = fmaxf(m0, m1);
    const float e0 = exp2f(m0 - M), e1 = exp2f(m1 - M);
    sAGG[tid] = (a0*e0 + a1*e1) / (s0*e0 + s1*e1);
    __syncthreads();
    float a = fin_b[tid] + ws[ib*64 + tid];      // + x1 residual
    #pragma unroll 16
    for (int c = 0; c < 64; ++c) a += sAGG[c] * fin_w[c*64 + tid];
    out[ib*64 + tid] = a;
}

// ---------------------------------------------------------------------------
extern "C" void kernel_launch(void* const* d_in, const int* in_sizes, int n_in,
                              void* d_out, int out_size, void* d_ws, size_t ws_size,
                              hipStream_t stream)
{
    const float* x       = (const float*)d_in[0];
    const float* pos     = (const float*)d_in[1];
    const float* prev_w  = (const float*)d_in[2];
    const float* prev_b  = (const float*)d_in[3];
    const float* q_w     = (const float*)d_in[4];
    const float* k_w     = (const float*)d_in[5];
    const float* v_w     = (const float*)d_in[6];
    const float* pos_w1  = (const float*)d_in[7];
    const float* pos_b1  = (const float*)d_in[8];
    const float* pos_w2  = (const float*)d_in[9];
    const float* pos_b2  = (const float*)d_in[10];
    const float* attn_w1 = (const float*)d_in[11];
    const float* attn_b1 = (const float*)d_in[12];
    const float* attn_w2 = (const float*)d_in[13];
    const float* attn_b2 = (const float*)d_in[14];
    const float* fin_w   = (const float*)d_in[15];
    const float* fin_b   = (const float*)d_in[16];
    float* out = (float*)d_out;
    float* ws  = (float*)d_ws;

    ptb_pre<<<272, 256, 0, stream>>>(x, pos, prev_w, prev_b, q_w, k_w, v_w,
                                     pos_w2, attn_w1, attn_b1, ws, out);
    ptb_main<<<2048, 256, 0, stream>>>(pos, pos_w1, pos_b1, pos_w2, pos_b2,
                                       attn_w2, attn_b2, ws, ws);
    ptb_fin<<<1024, 64, 0, stream>>>(fin_w, fin_b, ws, out);
}

// Round 17
// 105.832 us; speedup vs baseline: 1.0363x; 1.0363x over previous
//
#include <hip/hip_runtime.h>

typedef __attribute__((ext_vector_type(4))) float f32x4;
typedef __attribute__((ext_vector_type(8))) __bf16 bf16x8;
typedef __attribute__((ext_vector_type(4))) __bf16 bf16x4;
typedef __attribute__((ext_vector_type(2))) unsigned int u32x2;

// tr_read with compile-time offset folded into the DS immediate.
template<int OFF>
__device__ __forceinline__ u32x2 tr_read_o(unsigned base){
    u32x2 d;
    asm volatile("ds_read_b64_tr_b16 %0, %1 offset:%c2"
                 : "=v"(d) : "v"(base), "i"(OFF));
    return d;
}
__device__ __forceinline__ bf16x8 frag_cat(u32x2 a, u32x2 b){
    union { u32x2 u[2]; bf16x8 f; } c; c.u[0] = a; c.u[1] = b; return c.f;
}

// ws layout (floats):
//   x1   @ 0       (65536)
//   vs   @ 65536   (65536)    v row-group-swizzled [row/4][64][4]  (row GLOBAL)
//   Q1   @ 131072  (262144)   q@attn_w1 + attn_b1   [1024][256]
//   K1s  @ 393216  (262144)   k@attn_w1 row-group-swizzled [row/4][256][4]
//   W'   @ 655360  (16384)    pos_w2@attn_w1        [64][256]
//
// SESSION PLATEAU NOTE (round 17): this is the round-13 best (105.9us).
// Occupancy is hard-capped at 4 waves/SIMD: gfx950 VGPR allocation steps at
// 64/128/256 (m69) — VGPR 96 and 112 both land in the (64,128] bucket (round
// 16 proved 96 VGPR + 28KB LDS + 2048 grid still shows 20% occupancy). With
// 72 VGPR of irreducible weight fragments, <=64 is unreachable. Kernel is
// latency-bound at that cap; HBM 0.9%, MfmaUtil 16%, VALUBusy ~50%.

// ---------------------------------------------------------------------------
// Fused prologue: 272 blocks x 256.
// ---------------------------------------------------------------------------
__global__ void ptb_pre(const float* __restrict__ x,
                        const float* __restrict__ pos,
                        const float* __restrict__ prev_w,
                        const float* __restrict__ prev_b,
                        const float* __restrict__ q_w,
                        const float* __restrict__ k_w,
                        const float* __restrict__ v_w,
                        const float* __restrict__ pos_w2,
                        const float* __restrict__ attn_w1,
                        const float* __restrict__ attn_b1,
                        float* __restrict__ ws,
                        float* __restrict__ out)
{
    const int bid = blockIdx.x;
    const int tid = threadIdx.x;
    __shared__ float xr[256], x1r[256], qsh[256], ksh[256], vsh[256];

    float wcol[64];                       // attn_w1 column `tid`
    #pragma unroll
    for (int c = 0; c < 64; ++c) wcol[c] = attn_w1[c*256 + tid];

    if (bid >= 256){
        xr[tid] = pos_w2[(bid - 256)*256 + tid];
        __syncthreads();
        float* Wp = ws + 655360;
        #pragma unroll
        for (int r = 0; r < 4; ++r){
            float s = 0.f;
            #pragma unroll 16
            for (int c = 0; c < 64; ++c) s += xr[r*64 + c] * wcol[c];
            Wp[((bid - 256)*4 + r)*256 + tid] = s;
        }
        return;
    }

    const int rr  = tid >> 6, d = tid & 63;
    const int row = bid*4 + rr;
    xr[tid] = x[row*64 + d];
    __syncthreads();
    float a = prev_b[d];
    #pragma unroll 16
    for (int c = 0; c < 64; ++c) a += xr[rr*64 + c] * prev_w[c*64 + d];
    x1r[tid] = a;
    ws[row*64 + d] = a;
    __syncthreads();
    float qv = 0.f, kv = 0.f, vv = 0.f;
    #pragma unroll 16
    for (int c = 0; c < 64; ++c){
        float t = x1r[rr*64 + c];
        qv += t * q_w[c*64 + d];
        kv += t * k_w[c*64 + d];
        vv += t * v_w[c*64 + d];
    }
    qsh[tid] = qv; ksh[tid] = kv; vsh[tid] = vv;
    if (tid < 12) out[65536 + bid*12 + tid] = pos[bid*12 + tid];
    __syncthreads();

    // vs store: coalesced transpose via LDS -> vs[bid*256 + d'*4 + r']
    ws[65536 + bid*256 + tid] = vsh[(tid & 3)*64 + (tid >> 2)];

    float* Q1  = ws + 131072;
    float* K1s = ws + 393216;
    const float bb = attn_b1[tid];
    float sq[4], sk[4];
    #pragma unroll
    for (int r = 0; r < 4; ++r){ sq[r] = bb; sk[r] = 0.f; }
    #pragma unroll 16
    for (int c = 0; c < 64; ++c){
        const float wv = wcol[c];
        #pragma unroll
        for (int r = 0; r < 4; ++r){
            sq[r] += qsh[r*64 + c] * wv;
            sk[r] += ksh[r*64 + c] * wv;
        }
    }
    #pragma unroll
    for (int r = 0; r < 4; ++r) Q1[(bid*4 + r)*256 + tid] = sq[r];
    f32x4 kvec = {sk[0], sk[1], sk[2], sk[3]};
    *(f32x4*)&K1s[bid*1024 + tid*4] = kvec;
}

// ---------------------------------------------------------------------------
// Kernel B (round-13 best config, verbatim): 1024 blocks, sH1 dbuf, 144B
// sHT subtiles, cross-jj pipelined stage C, fused epilogue.
// ---------------------------------------------------------------------------
__global__ __launch_bounds__(256) void ptb_main(
    const float* __restrict__ pos,
    const float* __restrict__ pos_w1, const float* __restrict__ pos_b1,
    const float* __restrict__ pos_w2, const float* __restrict__ pos_b2,
    const float* __restrict__ attn_w2, const float* __restrict__ attn_b2,
    const float* __restrict__ fin_w, const float* __restrict__ fin_b,
    const float* __restrict__ ws, float* __restrict__ out)
{
    const int blk = blockIdx.x;
    const int b   = blk >> 9;
    const int i   = blk & 511;
    const int tid = threadIdx.x;
    const int w   = tid >> 6;
    const int l   = tid & 63;
    const int lg  = l >> 4;
    const int ln  = l & 15;

    // h1 tile (post-relu), XOR-swizzled 16B chunks: [buf][j][h ^ ((j&7)<<3)]
    __shared__ __bf16 sH1[2][64][64];            // 16 KB
    // H^T half-tile: 128 subtiles (jj*64+E) x 144B (128B data + 16B pad)
    __shared__ __align__(16) char sHT[18432];    // 18 KB
    __shared__ float sPW1[192], sPB1[64], sAGG[64], sPOSI[3];

    const float* x1p = ws;
    const float* vs  = ws + 65536;
    const float* Q1  = ws + 131072;
    const float* K1s = ws + 393216;
    const float* Wp  = ws + 655360;

    if (tid < 64) sPB1[tid] = pos_b1[tid];
    if (tid >= 64 && tid < 256) sPW1[tid - 64] = pos_w1[tid - 64];
    if (tid < 3) sPOSI[tid] = pos[(b*512 + i)*3 + tid];

    const int dch  = w*16 + ln;         // this lane's output channel (GEMM2)
    const int Ew   = w*64;              // this wave's hidden-col base (GEMM1')
    const int swzA = (ln & 7) << 3;     // sH1 h-chunk swizzle (row&7 == ln&7)

    // ---- register-resident weight B-fragments ----
    bf16x8 w1f[2][4];                   // W' frags
    #pragma unroll
    for (int kf = 0; kf < 2; ++kf)
        #pragma unroll
        for (int et = 0; et < 4; ++et)
            #pragma unroll
            for (int ii = 0; ii < 8; ++ii)
                w1f[kf][et][ii] = (__bf16)Wp[(kf*32 + lg*8 + ii)*256 + Ew + et*16 + ln];
    bf16x8 w2f[8];
    #pragma unroll
    for (int kf = 0; kf < 8; ++kf)
        #pragma unroll
        for (int ii = 0; ii < 8; ++ii)
            w2f[kf][ii] = (__bf16)attn_w2[(kf*32 + lg*8 + ii)*64 + dch];
    bf16x8 pwfw[2];                     // pos_w2 frags, this wave's d-slice only
    #pragma unroll
    for (int kf = 0; kf < 2; ++kf)
        #pragma unroll
        for (int ii = 0; ii < 8; ++ii)
            pwfw[kf][ii] = (__bf16)pos_w2[(kf*32 + lg*8 + ii)*64 + dch];

    float Q1b[4];
    #pragma unroll
    for (int et = 0; et < 4; ++et) Q1b[et] = Q1[blk*256 + Ew + et*16 + ln];
    const float pb2v = pos_b2[dch];
    const float b2v  = attn_b2[dch];

    const unsigned sHTb = (unsigned)(unsigned long long)&sHT[0];
    // per-lane tr_read base, loop-invariant: lg-group stride = 2 subtiles = 288B
    const unsigned trbase = sHTb + (unsigned)(lg*288 + ln*8);

    float mrun = -1e30f, srun = 0.f, arun = 0.f;

    // ---- stage A: h1 MLP only ----
    auto stageA = [&](int j0a){
        const int bufa = (j0a >> 6) & 1;
        const float* pj = &pos[(b*512 + j0a + w*16 + ln)*3];
        const float r0 = sPOSI[0] - pj[0];
        const float r1 = sPOSI[1] - pj[1];
        const float r2 = sPOSI[2] - pj[2];
        #pragma unroll
        for (int kf = 0; kf < 2; ++kf){
            const int hb = kf*32 + lg*8;
            f32x4 wa0 = *(const f32x4*)&sPW1[      hb],   wa1 = *(const f32x4*)&sPW1[      hb+4];
            f32x4 wb0 = *(const f32x4*)&sPW1[ 64 + hb],   wb1 = *(const f32x4*)&sPW1[ 64 + hb+4];
            f32x4 wc0 = *(const f32x4*)&sPW1[128 + hb],   wc1 = *(const f32x4*)&sPW1[128 + hb+4];
            f32x4 bb0 = *(const f32x4*)&sPB1[      hb],   bb1 = *(const f32x4*)&sPB1[      hb+4];
            bf16x8 h1f;
            #pragma unroll
            for (int ii = 0; ii < 4; ++ii){
                float hv0 = bb0[ii] + r0*wa0[ii] + r1*wb0[ii] + r2*wc0[ii];
                float hv1 = bb1[ii] + r0*wa1[ii] + r1*wb1[ii] + r2*wc1[ii];
                h1f[ii]   = (__bf16)fmaxf(hv0, 0.f);
                h1f[ii+4] = (__bf16)fmaxf(hv1, 0.f);
            }
            *(bf16x8*)&sH1[bufa][w*16 + ln][hb ^ swzA] = h1f;
        }
    };

    __syncthreads();
    stageA(0);

    #pragma unroll 1
    for (int t = 0; t < 8; ++t){
        const int j0  = t << 6;
        const int buf = t & 1;
        __syncthreads();                                    // B1
        if (t < 7) stageA(j0 + 64);                         // -> sH1[buf^1]
        #pragma unroll 1
        for (int hb = 0; hb < 2; ++hb){
            f32x4 rcs[2];                                   // rpe, carried B->C
            // ============== stage B half: GEMM1' + rpe ================
            #pragma unroll
            for (int jj = 0; jj < 2; ++jj){
                const int jrow = hb*32 + jj*16;
                const int krow = ((b*512 + j0 + jrow) >> 2) + lg;   // GLOBAL row group
                const bf16x8 af0 = *(const bf16x8*)&sH1[buf][jrow + ln][(     lg*8) ^ swzA];
                const bf16x8 af1 = *(const bf16x8*)&sH1[buf][jrow + ln][(32 + lg*8) ^ swzA];
                f32x4 accs[4];
                #pragma unroll
                for (int et = 0; et < 4; ++et){
                    const f32x4 kw4 = *(const f32x4*)&K1s[krow*1024 + (Ew + et*16 + ln)*4];
                    const f32x4 qv4 = {Q1b[et], Q1b[et], Q1b[et], Q1b[et]};
                    accs[et] = qv4 - kw4;
                }
                __builtin_amdgcn_s_setprio(1);
                #pragma unroll
                for (int et = 0; et < 4; ++et)
                    accs[et] = __builtin_amdgcn_mfma_f32_16x16x32_bf16(af0, w1f[0][et], accs[et], 0, 0, 0);
                #pragma unroll
                for (int et = 0; et < 4; ++et)
                    accs[et] = __builtin_amdgcn_mfma_f32_16x16x32_bf16(af1, w1f[1][et], accs[et], 0, 0, 0);
                f32x4 rcv = {pb2v, pb2v, pb2v, pb2v};
                rcv = __builtin_amdgcn_mfma_f32_16x16x32_bf16(af0, pwfw[0], rcv, 0, 0, 0);
                rcv = __builtin_amdgcn_mfma_f32_16x16x32_bf16(af1, pwfw[1], rcv, 0, 0, 0);
                rcs[jj] = rcv;
                __builtin_amdgcn_s_setprio(0);
                #pragma unroll
                for (int et = 0; et < 4; ++et){
                    bf16x4 hp;
                    #pragma unroll
                    for (int ri = 0; ri < 4; ++ri) hp[ri] = (__bf16)fmaxf(accs[et][ri], 0.f);
                    *(bf16x4*)(sHT + (jj*64 + w*16 + et*4 + (ln>>2))*144
                                   + (ln&3)*32 + lg*8) = hp;
                }
            }
            __syncthreads();                                // H half ready
            // ====== stage C half: cross-jj pipelined GEMM2 + softmax ==
            f32x4 accv[2], vvv[2];
            #pragma unroll
            for (int jj = 0; jj < 2; ++jj){
                const int vrow = ((b*512 + j0 + hb*32 + jj*16) >> 2) + lg;
                vvv[jj] = *(const f32x4*)&vs[vrow*256 + dch*4];
            }
            u32x2 h0[16], h1[16];
            // issue jj0's 16 reads (16 outstanding)
            #define TR2A(KF) \
                h0[(KF)*2]   = tr_read_o<(KF)*1152      >(trbase); \
                h0[(KF)*2+1] = tr_read_o<(KF)*1152 + 144>(trbase);
            TR2A(0) TR2A(1) TR2A(2) TR2A(3) TR2A(4) TR2A(5) TR2A(6) TR2A(7)
            #undef TR2A
            asm volatile("s_waitcnt lgkmcnt(8)" ::: "memory");   // h0[0..7] ready
            __builtin_amdgcn_sched_barrier(0);
            {
                f32x4 a0 = {b2v, b2v, b2v, b2v};
                f32x4 a1 = {0.f, 0.f, 0.f, 0.f};
                __builtin_amdgcn_s_setprio(1);
                a0 = __builtin_amdgcn_mfma_f32_16x16x32_bf16(frag_cat(h0[0], h0[1]), w2f[0], a0, 0, 0, 0);
                a1 = __builtin_amdgcn_mfma_f32_16x16x32_bf16(frag_cat(h0[2], h0[3]), w2f[1], a1, 0, 0, 0);
                a0 = __builtin_amdgcn_mfma_f32_16x16x32_bf16(frag_cat(h0[4], h0[5]), w2f[2], a0, 0, 0, 0);
                a1 = __builtin_amdgcn_mfma_f32_16x16x32_bf16(frag_cat(h0[6], h0[7]), w2f[3], a1, 0, 0, 0);
                __builtin_amdgcn_s_setprio(0);
                // issue jj1's first 8 (8 jj0-remain + 8 jj1 outstanding)
                const unsigned trb1 = trbase + 9216u;
                #define TR2B(KF) \
                    h1[(KF)*2]   = tr_read_o<(KF)*1152      >(trb1); \
                    h1[(KF)*2+1] = tr_read_o<(KF)*1152 + 144>(trb1);
                TR2B(0) TR2B(1) TR2B(2) TR2B(3)
                asm volatile("s_waitcnt lgkmcnt(8)" ::: "memory");  // h0[8..15] ready
                __builtin_amdgcn_sched_barrier(0);
                __builtin_amdgcn_s_setprio(1);
                a0 = __builtin_amdgcn_mfma_f32_16x16x32_bf16(frag_cat(h0[8],  h0[9]),  w2f[4], a0, 0, 0, 0);
                a1 = __builtin_amdgcn_mfma_f32_16x16x32_bf16(frag_cat(h0[10], h0[11]), w2f[5], a1, 0, 0, 0);
                a0 = __builtin_amdgcn_mfma_f32_16x16x32_bf16(frag_cat(h0[12], h0[13]), w2f[6], a0, 0, 0, 0);
                a1 = __builtin_amdgcn_mfma_f32_16x16x32_bf16(frag_cat(h0[14], h0[15]), w2f[7], a1, 0, 0, 0);
                __builtin_amdgcn_s_setprio(0);
                accv[0] = a0 + a1;
                // issue jj1's last 8 (16 outstanding)
                TR2B(4) TR2B(5) TR2B(6) TR2B(7)
                #undef TR2B
            }
            asm volatile("s_waitcnt lgkmcnt(8)" ::: "memory");   // h1[0..7] ready
            __builtin_amdgcn_sched_barrier(0);
            {
                f32x4 a0 = {b2v, b2v, b2v, b2v};
                f32x4 a1 = {0.f, 0.f, 0.f, 0.f};
                __builtin_amdgcn_s_setprio(1);
                a0 = __builtin_amdgcn_mfma_f32_16x16x32_bf16(frag_cat(h1[0], h1[1]), w2f[0], a0, 0, 0, 0);
                a1 = __builtin_amdgcn_mfma_f32_16x16x32_bf16(frag_cat(h1[2], h1[3]), w2f[1], a1, 0, 0, 0);
                a0 = __builtin_amdgcn_mfma_f32_16x16x32_bf16(frag_cat(h1[4], h1[5]), w2f[2], a0, 0, 0, 0);
                a1 = __builtin_amdgcn_mfma_f32_16x16x32_bf16(frag_cat(h1[6], h1[7]), w2f[3], a1, 0, 0, 0);
                __builtin_amdgcn_s_setprio(0);
                asm volatile("s_waitcnt lgkmcnt(0)" ::: "memory");
                __builtin_amdgcn_sched_barrier(0);
                __builtin_amdgcn_s_setprio(1);
                a0 = __builtin_amdgcn_mfma_f32_16x16x32_bf16(frag_cat(h1[8],  h1[9]),  w2f[4], a0, 0, 0, 0);
                a1 = __builtin_amdgcn_mfma_f32_16x16x32_bf16(frag_cat(h1[10], h1[11]), w2f[5], a1, 0, 0, 0);
                a0 = __builtin_amdgcn_mfma_f32_16x16x32_bf16(frag_cat(h1[12], h1[13]), w2f[6], a0, 0, 0, 0);
                a1 = __builtin_amdgcn_mfma_f32_16x16x32_bf16(frag_cat(h1[14], h1[15]), w2f[7], a1, 0, 0, 0);
                __builtin_amdgcn_s_setprio(0);
                accv[1] = a0 + a1;
            }
            // one deferred softmax update per half
            float tmax = fmaxf(fmaxf(fmaxf(accv[0][0], accv[0][1]),
                                     fmaxf(accv[0][2], accv[0][3])),
                               fmaxf(fmaxf(accv[1][0], accv[1][1]),
                                     fmaxf(accv[1][2], accv[1][3])));
            tmax = fmaxf(tmax, __shfl_xor(tmax, 16));
            tmax = fmaxf(tmax, __shfl_xor(tmax, 32));
            const float mnew  = fmaxf(mrun, tmax);
            const float scale = __expf(mrun - mnew);
            srun *= scale; arun *= scale; mrun = mnew;
            #pragma unroll
            for (int jj = 0; jj < 2; ++jj)
                #pragma unroll
                for (int ri = 0; ri < 4; ++ri){
                    const float p = __expf(accv[jj][ri] - mnew);
                    srun += p;
                    arun += p * (vvv[jj][ri] + rcs[jj][ri]);
                }
            if (hb == 0) __syncthreads();                   // WAR: sHT reuse
        }
        // loop top's B1 covers: sH1[buf] WAR vs A(t+2), sHT WAR vs Bhalf0(t+1)
    }

    arun += __shfl_xor(arun, 16); arun += __shfl_xor(arun, 32);
    srun += __shfl_xor(srun, 16); srun += __shfl_xor(srun, 32);
    if (lg == 0) sAGG[dch] = arun / srun;
    __syncthreads();

    if (tid < 64){
        float a = fin_b[tid] + x1p[blk*64 + tid];
        #pragma unroll 16
        for (int c = 0; c < 64; ++c) a += sAGG[c] * fin_w[c*64 + tid];
        out[blk*64 + tid] = a;
    }
}

// ---------------------------------------------------------------------------
extern "C" void kernel_launch(void* const* d_in, const int* in_sizes, int n_in,
                              void* d_out, int out_size, void* d_ws, size_t ws_size,
                              hipStream_t stream)
{
    const float* x       = (const float*)d_in[0];
    const float* pos     = (const float*)d_in[1];
    const float* prev_w  = (const float*)d_in[2];
    const float* prev_b  = (const float*)d_in[3];
    const float* q_w     = (const float*)d_in[4];
    const float* k_w     = (const float*)d_in[5];
    const float* v_w     = (const float*)d_in[6];
    const float* pos_w1  = (const float*)d_in[7];
    const float* pos_b1  = (const float*)d_in[8];
    const float* pos_w2  = (const float*)d_in[9];
    const float* pos_b2  = (const float*)d_in[10];
    const float* attn_w1 = (const float*)d_in[11];
    const float* attn_b1 = (const float*)d_in[12];
    const float* attn_w2 = (const float*)d_in[13];
    const float* attn_b2 = (const float*)d_in[14];
    const float* fin_w   = (const float*)d_in[15];
    const float* fin_b   = (const float*)d_in[16];
    float* out = (float*)d_out;
    float* ws  = (float*)d_ws;

    ptb_pre<<<272, 256, 0, stream>>>(x, pos, prev_w, prev_b, q_w, k_w, v_w,
                                     pos_w2, attn_w1, attn_b1, ws, out);
    ptb_main<<<1024, 256, 0, stream>>>(pos, pos_w1, pos_b1, pos_w2, pos_b2,
                                       attn_w2, attn_b2, fin_w, fin_b, ws, out);
}